// Round 1
// baseline (446.623 us; speedup 1.0000x reference)
//
#include <hip/hip_runtime.h>

// AdaptiveGraph on MI355X — restructured.
// K1 k_z : Z = X W^T via bf16 MFMA hi/lo split (fp32-accurate); writes Zb [n][h] + ZbT [h][n].
// K2 k_sv: per 128x128 tile: S = Z Z^T (MFMA), relu -> rowsum partials AND
//          V += bf16(relu(S)) @ Z (second MFMA vs ZbT tile). V is the UN-normalized out.
//          (out = diag(1/rowsum) * (relu(S) @ Z), so V needs no rowsum -> fuses here.)
// K3 k_a : lean A-writer: recompute S^T tiles, A = relu(S)*rsinv, nontemporal float4 stores.
//          No ZbT, no PT, no second MFMA, no atomics -> 34.8 KB LDS -> 4 blocks/CU.
// K4 k_out: out = Vacc * rsinv (8 MB stream).

#define NR 8192
#define KD 256
#define HD 128

typedef short v8s __attribute__((ext_vector_type(8)));
typedef float v4f __attribute__((ext_vector_type(4)));

static __device__ __forceinline__ ushort f2bf(float f) {
    union { float f; unsigned u; } c; c.f = f;
    unsigned u = c.u;
    u += 0x7fffu + ((u >> 16) & 1u);  // RNE; inputs finite
    return (ushort)(u >> 16);
}
static __device__ __forceinline__ float bf2f(ushort b) {
    union { unsigned u; float f; } c; c.u = ((unsigned)b) << 16; return c.f;
}
static __device__ __forceinline__ unsigned pk2(float a, float b) {
    union { float f; unsigned u; } x, y; x.f = a; y.f = b;
    unsigned ua = x.u + 0x7fffu + ((x.u >> 16) & 1u);
    unsigned ub = y.u + 0x7fffu + ((y.u >> 16) & 1u);
    return (ua >> 16) | (ub & 0xffff0000u);
}

// ---------------- K1: Z = X @ W^T (MFMA, hi/lo bf16 split) ----------------
__global__ __launch_bounds__(256) void k_z(const float* __restrict__ X,
                                           const float* __restrict__ W,
                                           ushort* __restrict__ Zb,
                                           ushort* __restrict__ ZbT) {
    __shared__ ushort Xhi[32][264];
    __shared__ ushort Xlo[32][264];
    int tid = threadIdx.x, lane = tid & 63, wave = tid >> 6;
    int lm = lane & 15, lq = lane >> 4;
    int n0 = blockIdx.x * 32;
    int hbase = wave * 32;
    v8s Whi[2][8], Wlo[2][8];
#pragma unroll
    for (int hi = 0; hi < 2; ++hi) {
        const float* wp = W + (hbase + hi * 16 + lm) * KD + lq * 8;
#pragma unroll
        for (int ks = 0; ks < 8; ++ks) {
            float4 w0 = *(const float4*)(wp + ks * 32);
            float4 w1 = *(const float4*)(wp + ks * 32 + 4);
            float wv[8] = {w0.x, w0.y, w0.z, w0.w, w1.x, w1.y, w1.z, w1.w};
#pragma unroll
            for (int j = 0; j < 8; ++j) {
                ushort h = f2bf(wv[j]);
                Whi[hi][ks][j] = (short)h;
                Wlo[hi][ks][j] = (short)f2bf(wv[j] - bf2f(h));
            }
        }
    }
#pragma unroll
    for (int t = 0; t < 8; ++t) {
        int idx = tid + t * 256;
        int r = idx >> 6, c4 = (idx & 63) * 4;
        float4 x = *(const float4*)(X + (size_t)(n0 + r) * KD + c4);
        ushort h0 = f2bf(x.x), h1 = f2bf(x.y), h2 = f2bf(x.z), h3 = f2bf(x.w);
        unsigned a = ((unsigned)h0) | ((unsigned)h1 << 16);
        unsigned b = ((unsigned)h2) | ((unsigned)h3 << 16);
        unsigned c = ((unsigned)f2bf(x.x - bf2f(h0))) | ((unsigned)f2bf(x.y - bf2f(h1)) << 16);
        unsigned d = ((unsigned)f2bf(x.z - bf2f(h2))) | ((unsigned)f2bf(x.w - bf2f(h3)) << 16);
        *(uint2*)&Xhi[r][c4] = make_uint2(a, b);
        *(uint2*)&Xlo[r][c4] = make_uint2(c, d);
    }
    __syncthreads();
#pragma unroll
    for (int ni = 0; ni < 2; ++ni) {
        v8s Ah[8], Al[8];
#pragma unroll
        for (int ks = 0; ks < 8; ++ks) {
            Ah[ks] = *(const v8s*)&Xhi[ni * 16 + lm][ks * 32 + lq * 8];
            Al[ks] = *(const v8s*)&Xlo[ni * 16 + lm][ks * 32 + lq * 8];
        }
        v4f acc[2] = {{0.f, 0.f, 0.f, 0.f}, {0.f, 0.f, 0.f, 0.f}};
#pragma unroll
        for (int ks = 0; ks < 8; ++ks)
#pragma unroll
            for (int hi = 0; hi < 2; ++hi) {
                acc[hi] = __builtin_amdgcn_mfma_f32_16x16x32_bf16(Ah[ks], Whi[hi][ks], acc[hi], 0, 0, 0);
                acc[hi] = __builtin_amdgcn_mfma_f32_16x16x32_bf16(Ah[ks], Wlo[hi][ks], acc[hi], 0, 0, 0);
                acc[hi] = __builtin_amdgcn_mfma_f32_16x16x32_bf16(Al[ks], Whi[hi][ks], acc[hi], 0, 0, 0);
            }
#pragma unroll
        for (int hi = 0; hi < 2; ++hi) {
            int h = hbase + hi * 16 + lm;
            int nb = n0 + ni * 16 + lq * 4;
            ushort b0 = f2bf(acc[hi][0]), b1 = f2bf(acc[hi][1]);
            ushort b2 = f2bf(acc[hi][2]), b3 = f2bf(acc[hi][3]);
            Zb[(size_t)(nb + 0) * HD + h] = b0;
            Zb[(size_t)(nb + 1) * HD + h] = b1;
            Zb[(size_t)(nb + 2) * HD + h] = b2;
            Zb[(size_t)(nb + 3) * HD + h] = b3;
            *(uint2*)&ZbT[(size_t)h * NR + nb] =
                make_uint2(((unsigned)b0) | ((unsigned)b1 << 16), ((unsigned)b2) | ((unsigned)b3 << 16));
        }
    }
}

// ---------------- K2: fused rowsum + V = relu(S) @ Z ----------------
// grid 512 = 64 rb x 8 cs; block tile 128r x (8 iters x 128c); 4 waves.
// S phase: wave = 64r x 64c (wr2,wc2). V phase: wave = 64r x 64h (wr2,wc2).
__global__ __launch_bounds__(256, 1) void k_sv(const ushort* __restrict__ Zb,
                                               const ushort* __restrict__ ZbT,
                                               float* __restrict__ rowsum,
                                               float* __restrict__ Vacc) {
    __shared__ ushort ZR[128][136];
    __shared__ ushort ZC[128][136];
    __shared__ ushort ZCT[128][136];  // Z^T tile [h][c-rel] for V B-operand
    __shared__ ushort PT[128][136];   // bf16(relu(S)) tile [r][c-rel]
    int tid = threadIdx.x, lane = tid & 63, wave = tid >> 6;
    int lm = lane & 15, lq = lane >> 4;
    int rb = blockIdx.x >> 3, cs = blockIdx.x & 7;
    int row0 = rb * 128, cstart = cs * 1024;
#pragma unroll
    for (int t = 0; t < 8; ++t) {
        int idx = tid + t * 256;
        int r = idx >> 4, c8 = (idx & 15) * 8;
        *(uint4*)&ZR[r][c8] = *(const uint4*)(Zb + (size_t)(row0 + r) * HD + c8);
    }
    __syncthreads();
    int wr2 = wave >> 1, wc2 = wave & 1;
    v8s Bfr[4][4];  // reg-cached ZR frags (B-operand for S^T)
#pragma unroll
    for (int ri = 0; ri < 4; ++ri)
#pragma unroll
        for (int ks = 0; ks < 4; ++ks)
            Bfr[ri][ks] = *(const v8s*)&ZR[wr2 * 64 + ri * 16 + lm][ks * 32 + lq * 8];
    float rs[4] = {0.f, 0.f, 0.f, 0.f};
    v4f V[4][4];  // [ri over r][hi over h]
#pragma unroll
    for (int ri = 0; ri < 4; ++ri)
#pragma unroll
        for (int hi = 0; hi < 4; ++hi) V[ri][hi] = (v4f){0.f, 0.f, 0.f, 0.f};

    for (int it = 0; it < 8; ++it) {
        int c0 = cstart + it * 128;
        __syncthreads();  // prev iter's reads of ZC/ZCT/PT done
#pragma unroll
        for (int t = 0; t < 8; ++t) {
            int idx = tid + t * 256;
            int r = idx >> 4, c8 = (idx & 15) * 8;
            *(uint4*)&ZC[r][c8] = *(const uint4*)(Zb + (size_t)(c0 + r) * HD + c8);
        }
#pragma unroll
        for (int t = 0; t < 8; ++t) {
            int idx = tid + t * 256;
            int h = idx >> 4, cc8 = (idx & 15) * 8;
            *(uint4*)&ZCT[h][cc8] = *(const uint4*)(ZbT + (size_t)h * NR + c0 + cc8);
        }
        __syncthreads();
        // S^T = (ZC as A) x (ZR as B): D[m=c][n=r] -> lane: r=lm, c=lq*4+reg
#pragma unroll
        for (int ci = 0; ci < 4; ++ci) {
            v8s Af[4];
#pragma unroll
            for (int ks = 0; ks < 4; ++ks)
                Af[ks] = *(const v8s*)&ZC[wc2 * 64 + ci * 16 + lm][ks * 32 + lq * 8];
            v4f acc[4] = {{0.f,0.f,0.f,0.f},{0.f,0.f,0.f,0.f},{0.f,0.f,0.f,0.f},{0.f,0.f,0.f,0.f}};
#pragma unroll
            for (int ks = 0; ks < 4; ++ks)
#pragma unroll
                for (int ri = 0; ri < 4; ++ri)
                    acc[ri] = __builtin_amdgcn_mfma_f32_16x16x32_bf16(Af[ks], Bfr[ri][ks], acc[ri], 0, 0, 0);
#pragma unroll
            for (int ri = 0; ri < 4; ++ri) {
                float a0 = fmaxf(acc[ri][0], 0.f), a1 = fmaxf(acc[ri][1], 0.f);
                float a2 = fmaxf(acc[ri][2], 0.f), a3 = fmaxf(acc[ri][3], 0.f);
                rs[ri] += a0 + a1 + a2 + a3;
                // PT[r][c-rel]: r = wr2*64+ri*16+lm, c-rel = wc2*64+ci*16+lq*4 (4 consecutive)
                *(uint2*)&PT[wr2 * 64 + ri * 16 + lm][wc2 * 64 + ci * 16 + lq * 4] =
                    make_uint2(pk2(a0, a1), pk2(a2, a3));
            }
        }
        __syncthreads();  // PT visible
        // V[r][h] += P[r][c] * Z[c][h]; A = PT frag (k=c), B = ZCT frag (k=c)
#pragma unroll
        for (int ks = 0; ks < 4; ++ks) {
            v8s Pf[4];
#pragma unroll
            for (int ri = 0; ri < 4; ++ri)
                Pf[ri] = *(const v8s*)&PT[wr2 * 64 + ri * 16 + lm][ks * 32 + lq * 8];
#pragma unroll
            for (int hi = 0; hi < 4; ++hi) {
                v8s Bz = *(const v8s*)&ZCT[wc2 * 64 + hi * 16 + lm][ks * 32 + lq * 8];
#pragma unroll
                for (int ri = 0; ri < 4; ++ri)
                    V[ri][hi] = __builtin_amdgcn_mfma_f32_16x16x32_bf16(Pf[ri], Bz, V[ri][hi], 0, 0, 0);
            }
        }
    }
    // rowsum reduce: lane sum over lq groups then one atomic per (r) per wave
#pragma unroll
    for (int ri = 0; ri < 4; ++ri) {
        float v = rs[ri];
        v += __shfl_xor(v, 16, 64);
        v += __shfl_xor(v, 32, 64);
        if (lq == 0) atomicAdd(&rowsum[row0 + wr2 * 64 + ri * 16 + lm], v);
    }
    // V epilogue: D layout -> r = row0+wr2*64+ri*16+lq*4+j, h = wc2*64+hi*16+lm
    // each Vacc address receives exactly 8 adds (one per cs) -> negligible contention
#pragma unroll
    for (int ri = 0; ri < 4; ++ri)
#pragma unroll
        for (int hi = 0; hi < 4; ++hi)
#pragma unroll
            for (int j = 0; j < 4; ++j)
                atomicAdd(&Vacc[(size_t)(row0 + wr2 * 64 + ri * 16 + lq * 4 + j) * HD +
                                wc2 * 64 + hi * 16 + lm],
                          V[ri][hi][j]);
}

// ---------------- K3: lean A writer ----------------
// grid 512 = 128 rb x 4 cs; block tile 64r x (32 iters x 64c); 34.8 KB LDS -> 4 blocks/CU.
__global__ __launch_bounds__(256, 4) void k_a(const ushort* __restrict__ Zb,
                                              const float* __restrict__ rowsum,
                                              float* __restrict__ Ap) {
    __shared__ ushort ZR[64][136];
    __shared__ ushort ZC[64][136];
    int tid = threadIdx.x, lane = tid & 63, wave = tid >> 6;
    int lm = lane & 15, lq = lane >> 4;
    int rb = blockIdx.x >> 2, cs = blockIdx.x & 3;
    int row0 = rb * 64, colb = cs * 2048;
#pragma unroll
    for (int t = 0; t < 4; ++t) {
        int idx = tid + t * 256;
        int r = idx >> 4, c8 = (idx & 15) * 8;
        *(uint4*)&ZR[r][c8] = *(const uint4*)(Zb + (size_t)(row0 + r) * HD + c8);
    }
    __syncthreads();
    int wr2 = wave >> 1, wc2 = wave & 1;
    v8s Bfr[2][4];
#pragma unroll
    for (int ri = 0; ri < 2; ++ri)
#pragma unroll
        for (int ks = 0; ks < 4; ++ks)
            Bfr[ri][ks] = *(const v8s*)&ZR[wr2 * 32 + ri * 16 + lm][ks * 32 + lq * 8];
    float rsv[2];
#pragma unroll
    for (int ri = 0; ri < 2; ++ri)
        rsv[ri] = 1.0f / (rowsum[row0 + wr2 * 32 + ri * 16 + lm] + 1e-6f);

    for (int it = 0; it < 32; ++it) {
        int c0 = colb + it * 64;
        __syncthreads();
#pragma unroll
        for (int t = 0; t < 4; ++t) {
            int idx = tid + t * 256;
            int r = idx >> 4, c8 = (idx & 15) * 8;
            *(uint4*)&ZC[r][c8] = *(const uint4*)(Zb + (size_t)(c0 + r) * HD + c8);
        }
        __syncthreads();
        // S^T: D[m=c][n=r] -> lane: r=lm, c=lq*4+reg (4 consecutive c -> float4 A-store)
#pragma unroll
        for (int ci = 0; ci < 2; ++ci) {
            v8s Af[4];
#pragma unroll
            for (int ks = 0; ks < 4; ++ks)
                Af[ks] = *(const v8s*)&ZC[wc2 * 32 + ci * 16 + lm][ks * 32 + lq * 8];
            v4f S0 = {0.f, 0.f, 0.f, 0.f}, S1 = {0.f, 0.f, 0.f, 0.f};
#pragma unroll
            for (int ks = 0; ks < 4; ++ks) {
                S0 = __builtin_amdgcn_mfma_f32_16x16x32_bf16(Af[ks], Bfr[0][ks], S0, 0, 0, 0);
                S1 = __builtin_amdgcn_mfma_f32_16x16x32_bf16(Af[ks], Bfr[1][ks], S1, 0, 0, 0);
            }
            int cb = wc2 * 32 + ci * 16 + lq * 4;
            {
                int r = wr2 * 32 + lm;
                v4f av;
                av[0] = fmaxf(S0[0], 0.f) * rsv[0]; av[1] = fmaxf(S0[1], 0.f) * rsv[0];
                av[2] = fmaxf(S0[2], 0.f) * rsv[0]; av[3] = fmaxf(S0[3], 0.f) * rsv[0];
                __builtin_nontemporal_store(av, (v4f*)(Ap + (size_t)(row0 + r) * NR + c0 + cb));
            }
            {
                int r = wr2 * 32 + 16 + lm;
                v4f av;
                av[0] = fmaxf(S1[0], 0.f) * rsv[1]; av[1] = fmaxf(S1[1], 0.f) * rsv[1];
                av[2] = fmaxf(S1[2], 0.f) * rsv[1]; av[3] = fmaxf(S1[3], 0.f) * rsv[1];
                __builtin_nontemporal_store(av, (v4f*)(Ap + (size_t)(row0 + r) * NR + c0 + cb));
            }
        }
    }
}

// ---------------- K4: out = Vacc * rsinv ----------------
__global__ __launch_bounds__(256) void k_out(const float* __restrict__ Vacc,
                                             const float* __restrict__ rowsum,
                                             float* __restrict__ outp) {
    int idx = blockIdx.x * 256 + threadIdx.x;  // float4 index, 262144 total
    int r = idx >> 5, h4 = (idx & 31) * 4;
    float rsv = 1.0f / (rowsum[r] + 1e-6f);
    float4 v = *(const float4*)(Vacc + (size_t)r * HD + h4);
    float4 o = make_float4(v.x * rsv, v.y * rsv, v.z * rsv, v.w * rsv);
    *(float4*)(outp + (size_t)r * HD + h4) = o;
}

extern "C" void kernel_launch(void* const* d_in, const int* in_sizes, int n_in,
                              void* d_out, int out_size, void* d_ws, size_t ws_size,
                              hipStream_t stream) {
    (void)in_sizes; (void)n_in; (void)out_size; (void)ws_size;
    const float* X = (const float*)d_in[0];
    const float* W = (const float*)d_in[1];
    float* outp = (float*)d_out;
    float* Ap = outp + (size_t)NR * HD;  // A follows out in d_out
    char* ws = (char*)d_ws;
    ushort* Zb = (ushort*)ws;                                   // 2 MB
    ushort* ZbT = (ushort*)(ws + (size_t)NR * HD * 2);          // 2 MB
    float* rowsum = (float*)(ws + (size_t)NR * HD * 4);         // 32 KB
    float* Vacc = (float*)(ws + (size_t)NR * HD * 4 + NR * 4);  // 4 MB

    (void)hipMemsetAsync(rowsum, 0, NR * sizeof(float), stream);
    (void)hipMemsetAsync(Vacc, 0, (size_t)NR * HD * sizeof(float), stream);
    k_z<<<dim3(NR / 32), dim3(256), 0, stream>>>(X, W, Zb, ZbT);
    k_sv<<<dim3(512), dim3(256), 0, stream>>>(Zb, ZbT, rowsum, Vacc);
    k_a<<<dim3(512), dim3(256), 0, stream>>>(Zb, rowsum, Ap);
    k_out<<<dim3(1024), dim3(256), 0, stream>>>(Vacc, rowsum, outp);
}